// Round 2
// baseline (34294.284 us; speedup 1.0000x reference)
//
#include <hip/hip_runtime.h>

#define T_STEPS 1024
#define BATCH   128
#define HID     128
#define GATES   512   // 4*HID
#define KDIM    256   // [x | h]
#define STACK   1024

__device__ __forceinline__ float sigf(float x) {
    return 1.0f / (1.0f + __expf(-x));
}
__device__ __forceinline__ float tanhfast(float x) {
    // tanh(x) = 1 - 2/(exp(2x)+1); saturates correctly at +/-inf
    return 1.0f - 2.0f / (1.0f + __expf(2.0f * x));
}

__launch_bounds__(1024, 1)
__global__ void stack_lstm_kernel(const float* __restrict__ inputs,
                                  const int*   __restrict__ ops,
                                  const float* __restrict__ w_ih,
                                  const float* __restrict__ w_hh,
                                  const float* __restrict__ b_ih,
                                  const float* __restrict__ b_hh,
                                  float* __restrict__ out)
{
    const int r   = blockIdx.x;   // batch row
    const int tid = threadIdx.x;  // 0..1023

    // LDS: double-buffered [x_t | h0_top], single [h0_new | h1_top], gates, ops
    __shared__ __align__(16) float xh0[2][KDIM];
    __shared__ __align__(16) float xh1[KDIM];
    __shared__ __align__(16) float g0[GATES];
    __shared__ __align__(16) float g1[GATES];
    __shared__ int ops_row[T_STEPS];

    const int layer = (tid < 512) ? 0 : 1;  // waves 0-7: layer0 rows, 8-15: layer1 rows
    const int o     = tid & 511;            // gate-row index within the layer

    // Persistent per-lane weights in VGPRs: one gate row, [W_ih | W_hh].
    // float4[32] x2 (64 aggregate elements, constant indices, address never
    // taken) so SROA promotes — the round-1 float[256]-through-a-pointer
    // version was demoted to scratch (VGPR=64, 61 GB of scratch refetch).
    float4 wi[32];
    float4 wh[32];
    {
        const float4* Wi = reinterpret_cast<const float4*>(w_ih + (size_t)(layer * GATES + o) * HID);
        const float4* Wh = reinterpret_cast<const float4*>(w_hh + (size_t)(layer * GATES + o) * HID);
#pragma unroll
        for (int k = 0; k < 32; ++k) wi[k] = Wi[k];
#pragma unroll
        for (int k = 0; k < 32; ++k) wh[k] = Wh[k];
    }
    const float bias = b_ih[layer * GATES + o] + b_hh[layer * GATES + o];

    // per-row ops into LDS (one-time, uncoalesced but tiny)
    ops_row[tid] = ops[(size_t)tid * BATCH + r];

    // init state
    if (tid < HID) {
        xh0[0][HID + tid] = 0.f;   // h0 at stack slot 0
        xh1[HID + tid]    = 0.f;   // h1 at stack slot 0
        xh0[0][tid] = inputs[(size_t)r * HID + tid];  // x_0
    }
    float c_cur = 0.f;  // lanes [0,128): c0[j];  lanes [512,640): c1[j]
    int   pos   = 0;    // tracked by lanes [512,640)
    __syncthreads();

    for (int t = 0; t < T_STEPS; ++t) {
        const int buf = t & 1;

        // ---- S0: layer-0 matvec (waves 0-7); x(t+1) prefetch (lanes 512-639) ----
        if (tid < 512) {
            const float4* xv = reinterpret_cast<const float4*>(xh0[buf]);
            float a0 = 0.f, a1 = 0.f, a2 = 0.f, a3 = 0.f;
#pragma unroll
            for (int k = 0; k < 32; ++k) {
                float4 x4 = xv[k];              // wave-uniform LDS broadcast
                a0 = fmaf(wi[k].x, x4.x, a0);
                a1 = fmaf(wi[k].y, x4.y, a1);
                a2 = fmaf(wi[k].z, x4.z, a2);
                a3 = fmaf(wi[k].w, x4.w, a3);
            }
#pragma unroll
            for (int k = 0; k < 32; ++k) {
                float4 h4 = xv[32 + k];
                a0 = fmaf(wh[k].x, h4.x, a0);
                a1 = fmaf(wh[k].y, h4.y, a1);
                a2 = fmaf(wh[k].z, h4.z, a2);
                a3 = fmaf(wh[k].w, h4.w, a3);
            }
            g0[o] = (a0 + a1) + (a2 + a3) + bias;
        } else if (tid < 512 + HID) {
            if (t + 1 < T_STEPS)
                xh0[buf ^ 1][tid - 512] =
                    inputs[(size_t)(t + 1) * BATCH * HID + (size_t)r * HID + (tid - 512)];
        }
        __syncthreads();

        // ---- S1: layer-0 epilogue (lanes 0..127) ----
        if (tid < HID) {
            const int op = ops_row[t];
            const float gi = g0[tid];
            const float gf = g0[HID + tid];
            const float gg = g0[2 * HID + tid];
            const float go = g0[3 * HID + tid];
            const float c_new = sigf(gf) * c_cur + sigf(gi) * tanhfast(gg);
            const float h_new = sigf(go) * tanhfast(c_new);
            xh1[tid] = h_new;                              // layer-1 input (every step)
            const float h_old = xh0[buf][HID + tid];
            xh0[buf ^ 1][HID + tid] = op ? h_new : h_old;  // frozen stack-top h0
            c_cur = op ? c_new : c_cur;                    // frozen stack-top c0
        }
        __syncthreads();

        // ---- S2: layer-1 matvec (waves 8-15) ----
        if (tid >= 512) {
            const float4* xv = reinterpret_cast<const float4*>(xh1);
            float a0 = 0.f, a1 = 0.f, a2 = 0.f, a3 = 0.f;
#pragma unroll
            for (int k = 0; k < 32; ++k) {
                float4 x4 = xv[k];
                a0 = fmaf(wi[k].x, x4.x, a0);
                a1 = fmaf(wi[k].y, x4.y, a1);
                a2 = fmaf(wi[k].z, x4.z, a2);
                a3 = fmaf(wi[k].w, x4.w, a3);
            }
#pragma unroll
            for (int k = 0; k < 32; ++k) {
                float4 h4 = xv[32 + k];
                a0 = fmaf(wh[k].x, h4.x, a0);
                a1 = fmaf(wh[k].y, h4.y, a1);
                a2 = fmaf(wh[k].z, h4.z, a2);
                a3 = fmaf(wh[k].w, h4.w, a3);
            }
            g1[o] = (a0 + a1) + (a2 + a3) + bias;
        }
        __syncthreads();

        // ---- S3: layer-1 epilogue + output stream (lanes 512..639) ----
        if (tid >= 512 && tid < 512 + HID) {
            const int j  = tid - 512;
            const int op = ops_row[t];
            const float gi = g1[j];
            const float gf = g1[HID + j];
            const float gg = g1[2 * HID + j];
            const float go = g1[3 * HID + j];
            const float c_new = sigf(gf) * c_cur + sigf(gi) * tanhfast(gg);
            const float h_new = sigf(go) * tanhfast(c_new);
            // contents[pos+1, r, j] — later writes to same slot legally overwrite
            out[(size_t)(pos + 1) * BATCH * HID + (size_t)r * HID + j] = h_new;
            const float h_old = xh1[HID + j];
            xh1[HID + j] = op ? h_new : h_old;  // frozen stack-top h1
            c_cur = op ? c_new : c_cur;         // frozen stack-top c1
            pos += op;
        }
        __syncthreads();
    }

    // final pos (as float32 — exact for integers <= 1024)
    if (tid == 512) {
        out[(size_t)(STACK + 1) * BATCH * HID + r] = (float)pos;
    }
}

extern "C" void kernel_launch(void* const* d_in, const int* in_sizes, int n_in,
                              void* d_out, int out_size, void* d_ws, size_t ws_size,
                              hipStream_t stream)
{
    (void)in_sizes; (void)n_in; (void)d_ws; (void)ws_size;
    const float* inputs = (const float*)d_in[0];
    const int*   ops    = (const int*)d_in[1];
    const float* w_ih   = (const float*)d_in[2];
    const float* w_hh   = (const float*)d_in[3];
    const float* b_ih   = (const float*)d_in[4];
    const float* b_hh   = (const float*)d_in[5];
    float* out = (float*)d_out;

    // slots never reached by pos+1 must be zero (harness poisons with 0xAA)
    hipMemsetAsync(d_out, 0, (size_t)out_size * sizeof(float), stream);

    stack_lstm_kernel<<<dim3(BATCH), dim3(1024), 0, stream>>>(
        inputs, ops, w_ih, w_hh, b_ih, b_hh, out);
}

// Round 3
// 12605.291 us; speedup vs baseline: 2.7206x; 2.7206x over previous
//
#include <hip/hip_runtime.h>

typedef _Float16 half2_t __attribute__((ext_vector_type(2)));

#define T_STEPS 1024
#define BATCH   128
#define HID     128
#define GATES   512
#define STACK   1024

__device__ __forceinline__ float sigf(float x)     { return 1.0f / (1.0f + __expf(-x)); }
__device__ __forceinline__ float tanhfast(float x) { return 1.0f - 2.0f / (1.0f + __expf(2.0f * x)); }

// padded gate index: breaks the 8-lane same-bank pattern on gate writes
__device__ __forceinline__ int PI(int r) { return r + (r >> 3); }

// grid = 256: blocks [0,128) = layer 0 of row r, [128,256) = layer 1 of row r.
// 512 threads = 8 waves -> 2 waves/SIMD -> 256 VGPR cap (weights need 128).
__launch_bounds__(512, 2)
__global__ void stack_lstm_pipe(const float* __restrict__ inputs,
                                const int*   __restrict__ ops,
                                const float* __restrict__ w_ih,
                                const float* __restrict__ w_hh,
                                const float* __restrict__ b_ih,
                                const float* __restrict__ b_hh,
                                float* __restrict__ out,
                                _Float16* __restrict__ h0_buf,  // [D][BATCH][HID]
                                int* __restrict__ prod,         // [BATCH]
                                int* __restrict__ cons,         // [BATCH]
                                int D)                          // ring depth, pow2
{
    const int bx    = blockIdx.x;
    const int layer = bx >> 7;      // 0 or 1
    const int r     = bx & 127;     // batch row
    const int tid   = threadIdx.x;  // 0..511
    const int g0    = tid >> 3;     // row group 0..63
    const int c     = tid & 7;      // K-chunk 0..7 (32 halfs each)
    const int mask  = D - 1;

    __shared__ _Float16 vin[256];             // [x-part | h-part] fp16
    __shared__ float    gl[GATES + GATES/8];  // padded gate scratch
    __shared__ int      ops_s[T_STEPS];

    // ---- per-lane weights: rows {g0+64j}, K-slice [c*32, c*32+32) => 128 half2 VGPRs
    half2_t w[128];
    {
        const float* base = (c < 4)
            ? (w_ih + (size_t)(layer * GATES) * HID + c * 32)
            : (w_hh + (size_t)(layer * GATES) * HID + (c - 4) * 32);
#pragma unroll
        for (int j = 0; j < 8; ++j) {
            const float* src = base + (size_t)(g0 + 64 * j) * HID;
#pragma unroll
            for (int kk = 0; kk < 16; ++kk) {
                float2 f = reinterpret_cast<const float2*>(src)[kk];
                half2_t h; h[0] = (_Float16)f.x; h[1] = (_Float16)f.y;
                w[j * 16 + kk] = h;
            }
        }
    }
    // after reduce-scatter this lane owns row g0 + 64*jstar
    const int   jstar   = ((c & 1) << 2) | (c & 2) | (c >> 2);
    const int   rowstar = g0 + 64 * jstar;
    const float bias    = b_ih[layer * GATES + rowstar] + b_hh[layer * GATES + rowstar];

    // stage this row's ops
    ops_s[tid]       = ops[(size_t)tid * BATCH + r];
    ops_s[tid + 512] = ops[(size_t)(tid + 512) * BATCH + r];

    // epilogue state (lanes 0..127)
    float    c_cur  = 0.f, h_top = 0.f;
    int      pos    = 0;
    float    xstage = 0.f;             // L0: next x (fp32)
    _Float16 hstage = (_Float16)0.f;   // L1: next h0_new (fp16)
    int      prod_seen = 0, cons_seen = 0;

    if (layer == 0) {
        if (tid < HID) xstage = inputs[(size_t)r * HID + tid];
    } else {
        if (tid == 0) {   // wait until L0 is >= 2 steps ahead, cache it
            int v;
            while ((v = __hip_atomic_load(prod + r, __ATOMIC_ACQUIRE,
                                          __HIP_MEMORY_SCOPE_AGENT)) < 2)
                __builtin_amdgcn_s_sleep(1);
            prod_seen = v;
        }
        __syncthreads();
        if (tid < HID) hstage = h0_buf[(size_t)r * HID + tid];  // slot 0
    }
    __syncthreads();

    for (int t = 0; t < T_STEPS; ++t) {
        // ---- S0: stage input vector, run protocol checks
        if (tid < HID) {
            vin[tid]       = (layer == 0) ? (_Float16)xstage : hstage;
            vin[HID + tid] = (_Float16)h_top;
        }
        if (tid == 0) {
            if (layer == 1 && t <= T_STEPS - 2) {
                const int tgt = t + 2;  // safe to prefetch slot t+1 in S1
                if (prod_seen < tgt) {
                    int v;
                    while ((v = __hip_atomic_load(prod + r, __ATOMIC_ACQUIRE,
                                                  __HIP_MEMORY_SCOPE_AGENT)) < tgt)
                        __builtin_amdgcn_s_sleep(1);
                    prod_seen = v;
                }
            }
            if (layer == 0 && t >= D) {  // ring backpressure (D=1024: never)
                const int tgt = t - D + 1;
                if (cons_seen < tgt) {
                    int v;
                    while ((v = __hip_atomic_load(cons + r, __ATOMIC_ACQUIRE,
                                                  __HIP_MEMORY_SCOPE_AGENT)) < tgt)
                        __builtin_amdgcn_s_sleep(1);
                    cons_seen = v;
                }
            }
        }
        __syncthreads();

        // ---- S1: 8-row x 32-K dot products (all 512 lanes)
        float p[8] = {0.f, 0.f, 0.f, 0.f, 0.f, 0.f, 0.f, 0.f};
        {
            const uint4* v4 = reinterpret_cast<const uint4*>(vin);
#pragma unroll
            for (int i = 0; i < 4; ++i) {
                const uint4 u = v4[c * 4 + i];
                const half2_t x0 = __builtin_bit_cast(half2_t, u.x);
                const half2_t x1 = __builtin_bit_cast(half2_t, u.y);
                const half2_t x2 = __builtin_bit_cast(half2_t, u.z);
                const half2_t x3 = __builtin_bit_cast(half2_t, u.w);
#pragma unroll
                for (int j = 0; j < 8; ++j) {
                    p[j] = __builtin_amdgcn_fdot2(w[j * 16 + 4 * i + 0], x0, p[j], false);
                    p[j] = __builtin_amdgcn_fdot2(w[j * 16 + 4 * i + 1], x1, p[j], false);
                    p[j] = __builtin_amdgcn_fdot2(w[j * 16 + 4 * i + 2], x2, p[j], false);
                    p[j] = __builtin_amdgcn_fdot2(w[j * 16 + 4 * i + 3], x3, p[j], false);
                }
            }
        }

        // prefetch next step's x / h0 (overlaps reduce)
        if (tid < HID && t + 1 < T_STEPS) {
            if (layer == 0)
                xstage = inputs[(size_t)(t + 1) * BATCH * HID + (size_t)r * HID + tid];
            else
                hstage = h0_buf[(size_t)((t + 1) & mask) * BATCH * HID + (size_t)r * HID + tid];
        }

        // ---- reduce-scatter over the 8-lane chunk group
        float total;
        {
            bool hi = (c & 1);
            float q0, q1, q2, q3;
            {
                float m0 = hi ? p[4] : p[0], s0 = hi ? p[0] : p[4];
                float m1 = hi ? p[5] : p[1], s1 = hi ? p[1] : p[5];
                float m2 = hi ? p[6] : p[2], s2 = hi ? p[2] : p[6];
                float m3 = hi ? p[7] : p[3], s3 = hi ? p[3] : p[7];
                q0 = m0 + __shfl_xor(s0, 1, 64);
                q1 = m1 + __shfl_xor(s1, 1, 64);
                q2 = m2 + __shfl_xor(s2, 1, 64);
                q3 = m3 + __shfl_xor(s3, 1, 64);
            }
            hi = (c & 2);
            float r0, r1;
            {
                float m0 = hi ? q2 : q0, s0 = hi ? q0 : q2;
                float m1 = hi ? q3 : q1, s1 = hi ? q1 : q3;
                r0 = m0 + __shfl_xor(s0, 2, 64);
                r1 = m1 + __shfl_xor(s1, 2, 64);
            }
            hi = (c & 4);
            float m0 = hi ? r1 : r0, s0 = hi ? r0 : r1;
            total = m0 + __shfl_xor(s0, 4, 64);
        }
        gl[PI(rowstar)] = total + bias;
        __syncthreads();

        // ---- S2: epilogue (lanes 0..127)
        if (tid < HID) {
            const int   op = ops_s[t];
            const float gi = gl[PI(tid)];
            const float gf = gl[PI(tid + 128)];
            const float gg = gl[PI(tid + 256)];
            const float go = gl[PI(tid + 384)];
            const float c_new = sigf(gf) * c_cur + sigf(gi) * tanhfast(gg);
            const float h_new = sigf(go) * tanhfast(c_new);
            if (layer == 0) {
                h0_buf[(size_t)(t & mask) * BATCH * HID + (size_t)r * HID + tid] =
                    (_Float16)h_new;
                __threadfence();  // order h0_buf store before prod release
            } else {
                out[(size_t)(pos + 1) * BATCH * HID + (size_t)r * HID + tid] = h_new;
                pos += op;
            }
            h_top = op ? h_new : h_top;
            c_cur = op ? c_new : c_cur;
        }
        __syncthreads();
        if (tid == 0) {
            if (layer == 0)
                __hip_atomic_store(prod + r, t + 1, __ATOMIC_RELEASE, __HIP_MEMORY_SCOPE_AGENT);
            else
                __hip_atomic_store(cons + r, t + 1, __ATOMIC_RELEASE, __HIP_MEMORY_SCOPE_AGENT);
        }
    }

    // final pos (float32 — exact for ints <= 1024)
    if (layer == 1 && tid == 0)
        out[(size_t)(STACK + 1) * BATCH * HID + r] = (float)pos;
}

extern "C" void kernel_launch(void* const* d_in, const int* in_sizes, int n_in,
                              void* d_out, int out_size, void* d_ws, size_t ws_size,
                              hipStream_t stream)
{
    (void)in_sizes; (void)n_in;
    const float* inputs = (const float*)d_in[0];
    const int*   ops    = (const int*)d_in[1];
    const float* w_ih   = (const float*)d_in[2];
    const float* w_hh   = (const float*)d_in[3];
    const float* b_ih   = (const float*)d_in[4];
    const float* b_hh   = (const float*)d_in[5];
    float* out = (float*)d_out;

    // ws layout: [0,4096) flags (prod 128 ints, cons 128 ints), then h0 ring
    int* prod = (int*)d_ws;
    int* cons = prod + 128;
    _Float16* h0_buf = (_Float16*)((char*)d_ws + 4096);

    // ring depth: largest pow2 slots that fit, capped at T_STEPS (no wrap)
    size_t slot_bytes = (size_t)BATCH * HID * sizeof(_Float16);
    size_t avail = (ws_size > 4096) ? (ws_size - 4096) / slot_bytes : 1;
    int D = 1;
    while ((size_t)(D * 2) <= avail && D < T_STEPS) D *= 2;

    hipMemsetAsync(d_ws, 0, 4096, stream);  // zero flags (ws is 0xAA-poisoned)
    // slots never reached by pos+1 must be zero
    hipMemsetAsync(d_out, 0, (size_t)out_size * sizeof(float), stream);

    stack_lstm_pipe<<<dim3(256), dim3(512), 0, stream>>>(
        inputs, ops, w_ih, w_hh, b_ih, b_hh, out, h0_buf, prod, cons, D);
}

// Round 4
// 1863.588 us; speedup vs baseline: 18.4023x; 6.7640x over previous
//
#include <hip/hip_runtime.h>

typedef _Float16 half2_t __attribute__((ext_vector_type(2)));

#define T_STEPS 1024
#define BATCH   128
#define HID     128
#define GATES   512
#define STACK   1024

__device__ __forceinline__ float sigf(float x)     { return 1.0f / (1.0f + __expf(-x)); }
__device__ __forceinline__ float tanhfast(float x) { return 1.0f - 2.0f / (1.0f + __expf(2.0f * x)); }

// padded gate index: breaks same-bank patterns on gate writes
__device__ __forceinline__ int PI(int r) { return r + (r >> 3); }

// grid = 256: blocks [0,128) = layer 0 of row r, [128,256) = layer 1 of row r.
// 512 threads = 8 waves -> 2 waves/SIMD -> 256 VGPR cap (weights need 128).
// ALL cross-block sync uses RELAXED agent-scope atomics: no buffer_wbl2 /
// buffer_inv L2 flushes (the round-3 12.6 ms was the per-step L2 flush storm
// from RELEASE/ACQUIRE + __threadfence). Ordering: __syncthreads drains
// vmcnt(0) for data-storing waves before tid0 stores the flag.
__launch_bounds__(512, 2)
__global__ void stack_lstm_pipe(const float* __restrict__ inputs,
                                const int*   __restrict__ ops,
                                const float* __restrict__ w_ih,
                                const float* __restrict__ w_hh,
                                const float* __restrict__ b_ih,
                                const float* __restrict__ b_hh,
                                float* __restrict__ out,
                                float* __restrict__ h0_buf,  // [D][BATCH][HID] fp32 ring
                                int* __restrict__ prod,      // [BATCH]
                                int* __restrict__ cons,      // [BATCH]
                                int D)                       // ring depth, pow2
{
    const int bx    = blockIdx.x;
    const int layer = bx >> 7;      // 0 or 1
    const int r     = bx & 127;     // batch row
    const int tid   = threadIdx.x;  // 0..511
    const int g0    = tid >> 3;     // row group 0..63
    const int c     = tid & 7;      // K-chunk 0..7 (32 halfs each)
    const int mask  = D - 1;

    __shared__ _Float16 vin[256];             // [x-part | h-part] fp16
    __shared__ float    gl[GATES + GATES/8];  // padded gate scratch
    __shared__ int      ops_s[T_STEPS];

    // ---- per-lane weights: rows {g0+64j}, K-slice [c*32, c*32+32) => 128 half2 VGPRs
    half2_t w[128];
    {
        const float* base = (c < 4)
            ? (w_ih + (size_t)(layer * GATES) * HID + c * 32)
            : (w_hh + (size_t)(layer * GATES) * HID + (c - 4) * 32);
#pragma unroll
        for (int j = 0; j < 8; ++j) {
            const float* src = base + (size_t)(g0 + 64 * j) * HID;
#pragma unroll
            for (int kk = 0; kk < 16; ++kk) {
                float2 f = reinterpret_cast<const float2*>(src)[kk];
                half2_t h; h[0] = (_Float16)f.x; h[1] = (_Float16)f.y;
                w[j * 16 + kk] = h;
            }
        }
    }
    // after reduce-scatter this lane owns row g0 + 64*jstar
    const int   jstar   = ((c & 1) << 2) | (c & 2) | (c >> 2);
    const int   rowstar = g0 + 64 * jstar;
    const float bias    = b_ih[layer * GATES + rowstar] + b_hh[layer * GATES + rowstar];

    // stage this row's ops
    ops_s[tid]       = ops[(size_t)tid * BATCH + r];
    ops_s[tid + 512] = ops[(size_t)(tid + 512) * BATCH + r];

    // epilogue state (lanes 0..127)
    float c_cur  = 0.f, h_top = 0.f;
    int   pos    = 0;
    float xstage = 0.f;   // L0: next x;  L1: next h0_new
    int   prod_seen = 0, cons_seen = 0;

    if (layer == 0) {
        if (tid < HID) xstage = inputs[(size_t)r * HID + tid];
    } else {
        if (tid == 0) {   // wait until L0 is >= 2 steps ahead
            int v;
            while ((v = __hip_atomic_load(prod + r, __ATOMIC_RELAXED,
                                          __HIP_MEMORY_SCOPE_AGENT)) < 2)
                __builtin_amdgcn_s_sleep(2);
            prod_seen = v;
        }
        __syncthreads();
        if (tid < HID) {  // slot 0 (bypassing loads: relaxed agent atomics)
            int bits = __hip_atomic_load(
                (int*)(h0_buf + (size_t)r * HID + tid),
                __ATOMIC_RELAXED, __HIP_MEMORY_SCOPE_AGENT);
            xstage = __builtin_bit_cast(float, bits);
        }
    }
    __syncthreads();

    for (int t = 0; t < T_STEPS; ++t) {
        // ---- S0: stage input vector, run protocol checks
        if (tid < HID) {
            vin[tid]       = (_Float16)xstage;
            vin[HID + tid] = (_Float16)h_top;
        }
        if (tid == 0) {
            if (layer == 1 && t <= T_STEPS - 2) {
                const int tgt = t + 2;  // safe to prefetch slot t+1 in S1
                if (prod_seen < tgt) {
                    int v;
                    while ((v = __hip_atomic_load(prod + r, __ATOMIC_RELAXED,
                                                  __HIP_MEMORY_SCOPE_AGENT)) < tgt)
                        __builtin_amdgcn_s_sleep(2);
                    prod_seen = v;
                }
            }
            if (layer == 0 && D < T_STEPS && t >= D) {  // ring backpressure
                const int tgt = t - D + 1;
                if (cons_seen < tgt) {
                    int v;
                    while ((v = __hip_atomic_load(cons + r, __ATOMIC_RELAXED,
                                                  __HIP_MEMORY_SCOPE_AGENT)) < tgt)
                        __builtin_amdgcn_s_sleep(2);
                    cons_seen = v;
                }
            }
        }
        __syncthreads();

        // ---- S1: 8-row x 32-K dot products (all 512 lanes)
        float p[8] = {0.f, 0.f, 0.f, 0.f, 0.f, 0.f, 0.f, 0.f};
        {
            const uint4* v4 = reinterpret_cast<const uint4*>(vin);
#pragma unroll
            for (int i = 0; i < 4; ++i) {
                const uint4 u = v4[c * 4 + i];
                const half2_t x0 = __builtin_bit_cast(half2_t, u.x);
                const half2_t x1 = __builtin_bit_cast(half2_t, u.y);
                const half2_t x2 = __builtin_bit_cast(half2_t, u.z);
                const half2_t x3 = __builtin_bit_cast(half2_t, u.w);
#pragma unroll
                for (int j = 0; j < 8; ++j) {
                    p[j] = __builtin_amdgcn_fdot2(w[j * 16 + 4 * i + 0], x0, p[j], false);
                    p[j] = __builtin_amdgcn_fdot2(w[j * 16 + 4 * i + 1], x1, p[j], false);
                    p[j] = __builtin_amdgcn_fdot2(w[j * 16 + 4 * i + 2], x2, p[j], false);
                    p[j] = __builtin_amdgcn_fdot2(w[j * 16 + 4 * i + 3], x3, p[j], false);
                }
            }
        }

        // prefetch next step's x / h0 (overlaps reduce)
        if (tid < HID && t + 1 < T_STEPS) {
            if (layer == 0) {
                xstage = inputs[(size_t)(t + 1) * BATCH * HID + (size_t)r * HID + tid];
            } else {
                int bits = __hip_atomic_load(
                    (int*)(h0_buf + (size_t)((t + 1) & mask) * BATCH * HID
                           + (size_t)r * HID + tid),
                    __ATOMIC_RELAXED, __HIP_MEMORY_SCOPE_AGENT);
                xstage = __builtin_bit_cast(float, bits);
            }
        }

        // ---- reduce-scatter over the 8-lane chunk group
        float total;
        {
            bool hi = (c & 1);
            float q0, q1, q2, q3;
            {
                float m0 = hi ? p[4] : p[0], s0 = hi ? p[0] : p[4];
                float m1 = hi ? p[5] : p[1], s1 = hi ? p[1] : p[5];
                float m2 = hi ? p[6] : p[2], s2 = hi ? p[2] : p[6];
                float m3 = hi ? p[7] : p[3], s3 = hi ? p[3] : p[7];
                q0 = m0 + __shfl_xor(s0, 1, 64);
                q1 = m1 + __shfl_xor(s1, 1, 64);
                q2 = m2 + __shfl_xor(s2, 1, 64);
                q3 = m3 + __shfl_xor(s3, 1, 64);
            }
            hi = (c & 2);
            float r0, r1;
            {
                float m0 = hi ? q2 : q0, s0 = hi ? q0 : q2;
                float m1 = hi ? q3 : q1, s1 = hi ? q1 : q3;
                r0 = m0 + __shfl_xor(s0, 2, 64);
                r1 = m1 + __shfl_xor(s1, 2, 64);
            }
            hi = (c & 4);
            float m0 = hi ? r1 : r0, s0 = hi ? r0 : r1;
            total = m0 + __shfl_xor(s0, 4, 64);
        }
        gl[PI(rowstar)] = total + bias;
        __syncthreads();

        // ---- S2: epilogue (lanes 0..127)
        if (tid < HID) {
            const int   op = ops_s[t];
            const float gi = gl[PI(tid)];
            const float gf = gl[PI(tid + 128)];
            const float gg = gl[PI(tid + 256)];
            const float go = gl[PI(tid + 384)];
            const float c_new = sigf(gf) * c_cur + sigf(gi) * tanhfast(gg);
            const float h_new = sigf(go) * tanhfast(c_new);
            if (layer == 0) {
                // write-through (sc1) store — no L2 flush needed for visibility
                __hip_atomic_store(
                    (int*)(h0_buf + (size_t)(t & mask) * BATCH * HID
                           + (size_t)r * HID + tid),
                    __builtin_bit_cast(int, h_new),
                    __ATOMIC_RELAXED, __HIP_MEMORY_SCOPE_AGENT);
            } else {
                out[(size_t)(pos + 1) * BATCH * HID + (size_t)r * HID + tid] = h_new;
                pos += op;
            }
            h_top = op ? h_new : h_top;
            c_cur = op ? c_new : c_cur;
        }
        // barrier drains vmcnt(0) for waves 0-1's data stores before tid0
        // releases the flag below — this IS the release ordering.
        __syncthreads();
        if (tid == 0) {
            if (layer == 0)
                __hip_atomic_store(prod + r, t + 1, __ATOMIC_RELAXED,
                                   __HIP_MEMORY_SCOPE_AGENT);
            else if (D < T_STEPS)
                __hip_atomic_store(cons + r, t + 1, __ATOMIC_RELAXED,
                                   __HIP_MEMORY_SCOPE_AGENT);
        }
    }

    // final pos (float32 — exact for ints <= 1024)
    if (layer == 1 && tid == 0)
        out[(size_t)(STACK + 1) * BATCH * HID + r] = (float)pos;
}

extern "C" void kernel_launch(void* const* d_in, const int* in_sizes, int n_in,
                              void* d_out, int out_size, void* d_ws, size_t ws_size,
                              hipStream_t stream)
{
    (void)in_sizes; (void)n_in;
    const float* inputs = (const float*)d_in[0];
    const int*   ops    = (const int*)d_in[1];
    const float* w_ih   = (const float*)d_in[2];
    const float* w_hh   = (const float*)d_in[3];
    const float* b_ih   = (const float*)d_in[4];
    const float* b_hh   = (const float*)d_in[5];
    float* out = (float*)d_out;

    // ws layout: [0,4096) flags (prod 128 ints, cons 128 ints), then fp32 ring
    int* prod = (int*)d_ws;
    int* cons = prod + 128;
    float* h0_buf = (float*)((char*)d_ws + 4096);

    // ring depth: largest pow2 slots that fit, capped at T_STEPS (no wrap)
    size_t slot_bytes = (size_t)BATCH * HID * sizeof(float);
    size_t avail = (ws_size > 4096) ? (ws_size - 4096) / slot_bytes : 1;
    int D = 1;
    while ((size_t)(D * 2) <= avail && D < T_STEPS) D *= 2;

    hipMemsetAsync(d_ws, 0, 4096, stream);  // zero flags (ws is 0xAA-poisoned)
    // slots never reached by pos+1 must be zero
    hipMemsetAsync(d_out, 0, (size_t)out_size * sizeof(float), stream);

    stack_lstm_pipe<<<dim3(256), dim3(512), 0, stream>>>(
        inputs, ops, w_ih, w_hh, b_ih, b_hh, out, h0_buf, prod, cons, D);
}

// Round 5
// 1367.229 us; speedup vs baseline: 25.0831x; 1.3630x over previous
//
#include <hip/hip_runtime.h>

typedef _Float16 half2_t __attribute__((ext_vector_type(2)));

#define T_STEPS 1024
#define BATCH   128
#define HID     128
#define GATES   512
#define STACK   1024

__device__ __forceinline__ float sigf(float x)     { return 1.0f / (1.0f + __expf(-x)); }
__device__ __forceinline__ float tanhfast(float x) { return 1.0f - 2.0f / (1.0f + __expf(2.0f * x)); }

// cross-lane xor helpers: xor1/xor2 are DPP quad_perm (VALU-rate), xor4 is ds_swizzle
__device__ __forceinline__ float xor1_dpp(float x) {
    int i = __builtin_bit_cast(int, x);
    i = __builtin_amdgcn_update_dpp(0, i, 0xB1, 0xF, 0xF, true);  // quad_perm [1,0,3,2]
    return __builtin_bit_cast(float, i);
}
__device__ __forceinline__ float xor2_dpp(float x) {
    int i = __builtin_bit_cast(int, x);
    i = __builtin_amdgcn_update_dpp(0, i, 0x4E, 0xF, 0xF, true);  // quad_perm [2,3,0,1]
    return __builtin_bit_cast(float, i);
}
__device__ __forceinline__ float xor4_swz(float x) {
    int i = __builtin_bit_cast(int, x);
    i = __builtin_amdgcn_ds_swizzle(i, 0x101F);                   // xor lane^4
    return __builtin_bit_cast(float, i);
}

// grid = 256: blocks [0,128) = layer 0 of row r, [128,256) = layer 1 of row r.
// One barrier per step. Cross-block: self-validating tagged u32 ring words
// (fp16 payload | step tag) — no flags, no fences, relaxed agent atomics only.
__launch_bounds__(512, 2)
__global__ void stack_lstm_pipe(const float* __restrict__ inputs,
                                const int*   __restrict__ ops,
                                const float* __restrict__ w_ih,
                                const float* __restrict__ w_hh,
                                const float* __restrict__ b_ih,
                                const float* __restrict__ b_hh,
                                float* __restrict__ out,
                                unsigned int* __restrict__ ring,  // [D][BATCH][HID]
                                int* __restrict__ cons,           // [BATCH] watermark
                                int D)                            // ring depth, pow2
{
    const int bx    = blockIdx.x;
    const int layer = bx >> 7;      // 0 or 1
    const int r     = bx & 127;     // batch row
    const int tid   = threadIdx.x;  // 0..511
    const int q     = tid >> 3;     // 0..63
    const int c     = tid & 7;      // K-chunk (32 halfs)
    const int e     = c & 1;
    const int u     = 64 * e + q;   // unit this lane's epilogue owns (4x redundant)
    const int mask  = D - 1;

    __shared__ __align__(16) _Float16 vin[2][256];  // [x(128) | h_top(128)], double-buffered
    __shared__ int ops_s[T_STEPS];

    // ---- weights: rows 64j+q (j=0..7), K-chunk c; order permuted to match the
    // conflict-free vin read pattern (uint4 index c+8i => halfs 8c+64i..+7)
    half2_t w[128];
#pragma unroll
    for (int j = 0; j < 8; ++j) {
        const float* rowi = w_ih + (size_t)(layer * GATES + 64 * j + q) * HID + 8 * c;
        const float* rowh = w_hh + (size_t)(layer * GATES + 64 * j + q) * HID + 8 * c;
#pragma unroll
        for (int i2 = 0; i2 < 2; ++i2)
#pragma unroll
            for (int j2 = 0; j2 < 4; ++j2) {
                float2 f = *reinterpret_cast<const float2*>(rowi + 64 * i2 + 2 * j2);
                half2_t h; h[0] = (_Float16)f.x; h[1] = (_Float16)f.y;
                w[j * 16 + i2 * 4 + j2] = h;
            }
#pragma unroll
        for (int i2 = 0; i2 < 2; ++i2)
#pragma unroll
            for (int j2 = 0; j2 < 4; ++j2) {
                float2 f = *reinterpret_cast<const float2*>(rowh + 64 * i2 + 2 * j2);
                half2_t h; h[0] = (_Float16)f.x; h[1] = (_Float16)f.y;
                w[j * 16 + 8 + i2 * 4 + j2] = h;
            }
    }
    // biases for the 4 gates of unit u (rows 128g + u)
    float B[4];
#pragma unroll
    for (int g = 0; g < 4; ++g)
        B[g] = b_ih[layer * GATES + 128 * g + u] + b_hh[layer * GATES + 128 * g + u];

    ops_s[tid]       = ops[(size_t)tid * BATCH + r];
    ops_s[tid + 512] = ops[(size_t)(tid + 512) * BATCH + r];

    const bool stager = (tid >= 128 && tid < 256);
    const int  su     = tid - 128;

    float c_cur = 0.f, h_top = 0.f;
    int   pos = 0, cons_seen = 0;
    float xs = 0.f;  // L0 stagers: x(t+1) pipeline register

    // ---- initial staging: vin[0] = [x(0) or h0(0) | zeros]
    if (stager) {
        if (layer == 0) {
            vin[0][su] = (_Float16)inputs[(size_t)r * HID + su];
            xs = inputs[(size_t)BATCH * HID + (size_t)r * HID + su];  // x(1)
        } else {
            unsigned int v;
            do {
                v = __hip_atomic_load(ring + (size_t)r * HID + su,
                                      __ATOMIC_RELAXED, __HIP_MEMORY_SCOPE_AGENT);
                if ((v & 0xFFFFu) == 1u) break;
                __builtin_amdgcn_s_sleep(1);
            } while (true);
            vin[0][su] = __builtin_bit_cast(_Float16, (unsigned short)(v >> 16));
        }
    }
    if (tid < HID) vin[0][HID + tid] = (_Float16)0.f;
    __syncthreads();

    for (int t = 0; t < T_STEPS; ++t) {
        const int buf = t & 1, nb = buf ^ 1;

        // speculative ring load for step t+1 (L1 stagers) — hides the round trip
        unsigned int spec = 0;
        if (layer == 1 && stager && t + 1 < T_STEPS)
            spec = __hip_atomic_load(ring + (size_t)((t + 1) & mask) * BATCH * HID
                                          + (size_t)r * HID + su,
                                     __ATOMIC_RELAXED, __HIP_MEMORY_SCOPE_AGENT);

        // ---- dots: 8 rows x 32-K per lane, conflict-free vin reads
        float p[8] = {0.f, 0.f, 0.f, 0.f, 0.f, 0.f, 0.f, 0.f};
        {
            const uint4* v4 = reinterpret_cast<const uint4*>(&vin[buf][0]);
#pragma unroll
            for (int i = 0; i < 4; ++i) {
                const uint4 u4 = v4[c + 8 * i];   // banks disjoint per c
                const half2_t x0 = __builtin_bit_cast(half2_t, u4.x);
                const half2_t x1 = __builtin_bit_cast(half2_t, u4.y);
                const half2_t x2 = __builtin_bit_cast(half2_t, u4.z);
                const half2_t x3 = __builtin_bit_cast(half2_t, u4.w);
#pragma unroll
                for (int j = 0; j < 8; ++j) {
                    p[j] = __builtin_amdgcn_fdot2(w[j * 16 + i * 4 + 0], x0, p[j], false);
                    p[j] = __builtin_amdgcn_fdot2(w[j * 16 + i * 4 + 1], x1, p[j], false);
                    p[j] = __builtin_amdgcn_fdot2(w[j * 16 + i * 4 + 2], x2, p[j], false);
                    p[j] = __builtin_amdgcn_fdot2(w[j * 16 + i * 4 + 3], x3, p[j], false);
                }
            }
        }

        // ---- reduce: level1 scatter row-parity, levels 2-3 all-reduce
        float vv[4];
#pragma unroll
        for (int g = 0; g < 4; ++g) {
            const float m = e ? p[2 * g + 1] : p[2 * g];
            const float s = e ? p[2 * g] : p[2 * g + 1];
            vv[g] = m + xor1_dpp(s);
        }
#pragma unroll
        for (int g = 0; g < 4; ++g) vv[g] += xor2_dpp(vv[g]);
#pragma unroll
        for (int g = 0; g < 4; ++g) vv[g] += xor4_swz(vv[g]);
        // lane now holds gates i,f,g,o of unit u (replicated over c>>1)

        // ---- epilogue (every lane, 4x redundant => no extra barrier)
        const int   op    = ops_s[t];
        const float c_new = sigf(vv[1] + B[1]) * c_cur
                          + sigf(vv[0] + B[0]) * tanhfast(vv[2] + B[2]);
        const float h_new = sigf(vv[3] + B[3]) * tanhfast(c_new);

        if (c < 2) {  // unique writer per unit
            if (layer == 0) {
                const unsigned short hs = __builtin_bit_cast(unsigned short, (_Float16)h_new);
                if (D < T_STEPS && t >= D) {  // ring backpressure (rare)
                    const int need = t - D;
                    while (cons_seen < need) {
                        cons_seen = __hip_atomic_load(cons + r, __ATOMIC_RELAXED,
                                                      __HIP_MEMORY_SCOPE_AGENT);
                        if (cons_seen >= need) break;
                        __builtin_amdgcn_s_sleep(1);
                    }
                }
                __hip_atomic_store(ring + (size_t)(t & mask) * BATCH * HID
                                        + (size_t)r * HID + u,
                                   ((unsigned int)hs << 16) | (unsigned int)((t + 1) & 0xFFFF),
                                   __ATOMIC_RELAXED, __HIP_MEMORY_SCOPE_AGENT);
            } else {
                out[(size_t)(pos + 1) * BATCH * HID + (size_t)r * HID + u] = h_new;
            }
            vin[nb][HID + u] = (_Float16)(op ? h_new : h_top);
        }
        h_top = op ? h_new : h_top;
        c_cur = op ? c_new : c_cur;
        pos += op;

        // ---- stage next step's x-part
        if (stager && t + 1 < T_STEPS) {
            if (layer == 0) {
                vin[nb][su] = (_Float16)xs;
                if (t + 2 < T_STEPS)
                    xs = inputs[(size_t)(t + 2) * BATCH * HID + (size_t)r * HID + su];
            } else {
                unsigned int v = spec;
                const unsigned int expect = (unsigned int)((t + 2) & 0xFFFF);
                while ((v & 0xFFFFu) != expect) {
                    __builtin_amdgcn_s_sleep(1);
                    v = __hip_atomic_load(ring + (size_t)((t + 1) & mask) * BATCH * HID
                                               + (size_t)r * HID + su,
                                          __ATOMIC_RELAXED, __HIP_MEMORY_SCOPE_AGENT);
                }
                vin[nb][su] = __builtin_bit_cast(_Float16, (unsigned short)(v >> 16));
            }
        }
        // consumer progress watermark (backpressure input; relaxed, lag-safe)
        if (layer == 1 && tid == 256 && (t & 15) == 0)
            __hip_atomic_store(cons + r, t - 1, __ATOMIC_RELAXED, __HIP_MEMORY_SCOPE_AGENT);

        __syncthreads();  // the ONE barrier per step
    }

    // final pos (float32 — exact for ints <= 1024)
    if (layer == 1 && tid == 0)
        out[(size_t)(STACK + 1) * BATCH * HID + r] = (float)pos;
}

extern "C" void kernel_launch(void* const* d_in, const int* in_sizes, int n_in,
                              void* d_out, int out_size, void* d_ws, size_t ws_size,
                              hipStream_t stream)
{
    (void)in_sizes; (void)n_in;
    const float* inputs = (const float*)d_in[0];
    const int*   ops    = (const int*)d_in[1];
    const float* w_ih   = (const float*)d_in[2];
    const float* w_hh   = (const float*)d_in[3];
    const float* b_ih   = (const float*)d_in[4];
    const float* b_hh   = (const float*)d_in[5];
    float* out = (float*)d_out;

    // ws layout: [0,4096) cons watermark, then tagged u32 ring [D][128][128]
    int* cons = (int*)d_ws;
    unsigned int* ring = (unsigned int*)((char*)d_ws + 4096);

    size_t slot_bytes = (size_t)BATCH * HID * sizeof(unsigned int);
    size_t avail = (ws_size > 4096) ? (ws_size - 4096) / slot_bytes : 1;
    int D = 1;
    while ((size_t)(D * 2) <= avail && D < T_STEPS) D *= 2;

    hipMemsetAsync(d_ws, 0, 4096, stream);  // zero watermarks
    // ring starts 0xAA-poisoned: tag 0xAAAA never matches (expect <= 1025)
    // slots never reached by pos+1 must be zero
    hipMemsetAsync(d_out, 0, (size_t)out_size * sizeof(float), stream);

    stack_lstm_pipe<<<dim3(256), dim3(512), 0, stream>>>(
        inputs, ops, w_ih, w_hh, b_ih, b_hh, out, ring, cons, D);
}

// Round 6
// 1358.439 us; speedup vs baseline: 25.2454x; 1.0065x over previous
//
#include <hip/hip_runtime.h>

typedef _Float16 half8_t __attribute__((ext_vector_type(8)));
typedef float    f32x4   __attribute__((ext_vector_type(4)));

#define T_STEPS 1024
#define BATCH   128
#define HID     128
#define GATES   512
#define STACK   1024

__device__ __forceinline__ float sigf(float x)     { return 1.0f / (1.0f + __expf(-x)); }
__device__ __forceinline__ float tanhfast(float x) { return 1.0f - 2.0f / (1.0f + __expf(2.0f * x)); }

// grid = 256: blocks [0,128) = layer 0 of row r, [128,256) = layer 1 of row r.
// Matvec runs on the MFMA pipe (16x16x32 f16, N=1 broadcast-B: every C column
// equals the matvec, so no B masking). Weights persist as A-fragments in
// AGPRs (MFMA reads them directly — kills the accvgpr_read tax that made
// round 5 VALU-issue-bound at 69% VALUBusy).
// Cross-block: self-validating tagged u32 ring words, relaxed agent atomics.
__launch_bounds__(512, 2)
__global__ void stack_lstm_pipe(const float* __restrict__ inputs,
                                const int*   __restrict__ ops,
                                const float* __restrict__ w_ih,
                                const float* __restrict__ w_hh,
                                const float* __restrict__ b_ih,
                                const float* __restrict__ b_hh,
                                float* __restrict__ out,
                                unsigned int* __restrict__ ring,  // [D][BATCH][HID]
                                int* __restrict__ cons,           // [BATCH] watermark
                                int D)                            // ring depth, pow2
{
    const int bx    = blockIdx.x;
    const int layer = bx >> 7;      // 0 or 1
    const int r     = bx & 127;     // batch row
    const int tid   = threadIdx.x;  // 0..511
    const int wv    = tid >> 6;     // wave 0..7 -> gate rows [64wv, 64wv+64)
    const int ln    = tid & 63;
    const int ml    = ln & 15;      // m within 16x16 tile
    const int kg    = ln >> 4;      // k-group 0..3
    const int u     = tid & 127;    // unit this lane's epilogue owns (4x redundant)
    const int mask  = D - 1;

    __shared__ __align__(16) _Float16 vin[2][256];  // [x(128) | h_top(128)]
    __shared__ __align__(16) float    gl[GATES];    // gate scratch
    __shared__ int ops_s[T_STEPS];

    // ---- weights as MFMA A-fragments: tile i (0..3) covers gate rows
    // [64wv+16i, +16); frag element A[m=ml][k=8kg+j] of K-chunk kc.
    // Virtual K-axis: k<128 -> w_ih cols, k>=128 -> w_hh cols.
    half8_t wfrag[32];  // [i*8 + kc]
#pragma unroll
    for (int i = 0; i < 4; ++i) {
        const int R = 64 * wv + 16 * i + ml;
        const float* rowi = w_ih + (size_t)(layer * GATES + R) * HID;
        const float* rowh = w_hh + (size_t)(layer * GATES + R) * HID;
#pragma unroll
        for (int kc = 0; kc < 8; ++kc) {
            const int k0 = 32 * kc + 8 * kg;
            const float* src = (k0 < 128) ? (rowi + k0) : (rowh + (k0 - 128));
            half8_t h;
#pragma unroll
            for (int j = 0; j < 8; j += 2) {
                float2 f = *reinterpret_cast<const float2*>(src + j);
                h[j]     = (_Float16)f.x;
                h[j + 1] = (_Float16)f.y;
            }
            wfrag[i * 8 + kc] = h;
        }
    }
    // biases for the 4 gates of unit u (gate rows 128g + u)
    float B[4];
#pragma unroll
    for (int g = 0; g < 4; ++g)
        B[g] = b_ih[layer * GATES + 128 * g + u] + b_hh[layer * GATES + 128 * g + u];

    ops_s[tid]       = ops[(size_t)tid * BATCH + r];
    ops_s[tid + 512] = ops[(size_t)(tid + 512) * BATCH + r];

    const bool stager = (tid >= 128 && tid < 256);
    const int  su     = tid - 128;

    float c_cur = 0.f, h_top = 0.f;
    int   pos = 0, cons_seen = 0;
    float xs = 0.f;  // L0 stagers: x(t+1) pipeline register

    // ---- initial staging: vin[0] = [x(0) or h0(0) | zeros]
    if (stager) {
        if (layer == 0) {
            vin[0][su] = (_Float16)inputs[(size_t)r * HID + su];
            xs = inputs[(size_t)BATCH * HID + (size_t)r * HID + su];  // x(1)
        } else {
            unsigned int v;
            do {
                v = __hip_atomic_load(ring + (size_t)r * HID + su,
                                      __ATOMIC_RELAXED, __HIP_MEMORY_SCOPE_AGENT);
                if ((v & 0xFFFFu) == 1u) break;
                __builtin_amdgcn_s_sleep(1);
            } while (true);
            vin[0][su] = __builtin_bit_cast(_Float16, (unsigned short)(v >> 16));
        }
    }
    if (tid < HID) vin[0][HID + tid] = (_Float16)0.f;
    __syncthreads();

    for (int t = 0; t < T_STEPS; ++t) {
        const int buf = t & 1, nb = buf ^ 1;

        // speculative ring load for step t+1 (L1 stagers) — hides the round trip
        unsigned int spec = 0;
        if (layer == 1 && stager && t + 1 < T_STEPS)
            spec = __hip_atomic_load(ring + (size_t)((t + 1) & mask) * BATCH * HID
                                          + (size_t)r * HID + su,
                                     __ATOMIC_RELAXED, __HIP_MEMORY_SCOPE_AGENT);

        // ---- S1: matvec on the MFMA pipe. B-frag address is lane&15-free:
        // all lanes broadcast-load the same vector chunk, so all 16 C columns
        // hold the matvec result (no masking needed).
        f32x4 a0 = {0.f, 0.f, 0.f, 0.f}, a1 = a0, a2 = a0, a3 = a0;
#pragma unroll
        for (int kc = 0; kc < 8; ++kc) {
            const half8_t bfrag =
                *reinterpret_cast<const half8_t*>(&vin[buf][32 * kc + 8 * kg]);
            a0 = __builtin_amdgcn_mfma_f32_16x16x32_f16(wfrag[kc],      bfrag, a0, 0, 0, 0);
            a1 = __builtin_amdgcn_mfma_f32_16x16x32_f16(wfrag[8 + kc],  bfrag, a1, 0, 0, 0);
            a2 = __builtin_amdgcn_mfma_f32_16x16x32_f16(wfrag[16 + kc], bfrag, a2, 0, 0, 0);
            a3 = __builtin_amdgcn_mfma_f32_16x16x32_f16(wfrag[24 + kc], bfrag, a3, 0, 0, 0);
        }
        // C layout: col=lane&15, row=4*kg+reg. Column 0 writers (ml==0) store
        // rows 64wv+16i+4kg..+3 as one b128 each; active-lane addrs 16B apart.
        if (ml == 0) {
            *reinterpret_cast<f32x4*>(&gl[64 * wv      + 4 * kg]) = a0;
            *reinterpret_cast<f32x4*>(&gl[64 * wv + 16 + 4 * kg]) = a1;
            *reinterpret_cast<f32x4*>(&gl[64 * wv + 32 + 4 * kg]) = a2;
            *reinterpret_cast<f32x4*>(&gl[64 * wv + 48 + 4 * kg]) = a3;
        }
        __syncthreads();  // barrier A: gl complete

        // ---- S2: epilogue (all lanes, 4x redundant; unique writers tid<128)
        const int   op  = ops_s[t];
        const float gi  = gl[u];
        const float gf  = gl[128 + u];
        const float gg  = gl[256 + u];
        const float go  = gl[384 + u];
        const float c_new = sigf(gf + B[1 * 0 + 1]) * c_cur  // B[1]
                          + sigf(gi + B[0]) * tanhfast(gg + B[2]);
        const float h_new = sigf(go + B[3]) * tanhfast(c_new);

        if (tid < 128) {
            if (layer == 0) {
                const unsigned short hs = __builtin_bit_cast(unsigned short, (_Float16)h_new);
                if (D < T_STEPS && t >= D) {  // ring backpressure (rare)
                    const int need = t - D;
                    while (cons_seen < need) {
                        cons_seen = __hip_atomic_load(cons + r, __ATOMIC_RELAXED,
                                                      __HIP_MEMORY_SCOPE_AGENT);
                        if (cons_seen >= need) break;
                        __builtin_amdgcn_s_sleep(1);
                    }
                }
                __hip_atomic_store(ring + (size_t)(t & mask) * BATCH * HID
                                        + (size_t)r * HID + u,
                                   ((unsigned int)hs << 16) | (unsigned int)((t + 1) & 0xFFFF),
                                   __ATOMIC_RELAXED, __HIP_MEMORY_SCOPE_AGENT);
            } else {
                out[(size_t)(pos + 1) * BATCH * HID + (size_t)r * HID + u] = h_new;
            }
            vin[nb][HID + u] = (_Float16)(op ? h_new : h_top);
        }
        h_top = op ? h_new : h_top;
        c_cur = op ? c_new : c_cur;
        pos += op;

        // ---- stage next step's x-part
        if (stager && t + 1 < T_STEPS) {
            if (layer == 0) {
                vin[nb][su] = (_Float16)xs;
                if (t + 2 < T_STEPS)
                    xs = inputs[(size_t)(t + 2) * BATCH * HID + (size_t)r * HID + su];
            } else {
                unsigned int v = spec;
                const unsigned int expect = (unsigned int)((t + 2) & 0xFFFF);
                while ((v & 0xFFFFu) != expect) {
                    __builtin_amdgcn_s_sleep(1);
                    v = __hip_atomic_load(ring + (size_t)((t + 1) & mask) * BATCH * HID
                                               + (size_t)r * HID + su,
                                          __ATOMIC_RELAXED, __HIP_MEMORY_SCOPE_AGENT);
                }
                vin[nb][su] = __builtin_bit_cast(_Float16, (unsigned short)(v >> 16));
            }
        }
        // consumer progress watermark (backpressure input; relaxed, lag-safe)
        if (layer == 1 && tid == 256 && (t & 15) == 0)
            __hip_atomic_store(cons + r, t - 1, __ATOMIC_RELAXED, __HIP_MEMORY_SCOPE_AGENT);

        __syncthreads();  // barrier B: vin[nb] complete, gl reads drained
    }

    // final pos (float32 — exact for ints <= 1024)
    if (layer == 1 && tid == 0)
        out[(size_t)(STACK + 1) * BATCH * HID + r] = (float)pos;
}

extern "C" void kernel_launch(void* const* d_in, const int* in_sizes, int n_in,
                              void* d_out, int out_size, void* d_ws, size_t ws_size,
                              hipStream_t stream)
{
    (void)in_sizes; (void)n_in;
    const float* inputs = (const float*)d_in[0];
    const int*   ops    = (const int*)d_in[1];
    const float* w_ih   = (const float*)d_in[2];
    const float* w_hh   = (const float*)d_in[3];
    const float* b_ih   = (const float*)d_in[4];
    const float* b_hh   = (const float*)d_in[5];
    float* out = (float*)d_out;

    // ws layout: [0,4096) cons watermark, then tagged u32 ring [D][128][128]
    int* cons = (int*)d_ws;
    unsigned int* ring = (unsigned int*)((char*)d_ws + 4096);

    size_t slot_bytes = (size_t)BATCH * HID * sizeof(unsigned int);
    size_t avail = (ws_size > 4096) ? (ws_size - 4096) / slot_bytes : 1;
    int D = 1;
    while ((size_t)(D * 2) <= avail && D < T_STEPS) D *= 2;

    hipMemsetAsync(d_ws, 0, 4096, stream);  // zero watermarks
    // ring starts 0xAA-poisoned: tag 0xAAAA never matches (expect <= 1025)
    // slots never reached by pos+1 must be zero
    hipMemsetAsync(d_out, 0, (size_t)out_size * sizeof(float), stream);

    stack_lstm_pipe<<<dim3(256), dim3(512), 0, stream>>>(
        inputs, ops, w_ih, w_hh, b_ih, b_hh, out, ring, cons, D);
}